// Round 11
// baseline (256.382 us; speedup 1.0000x reference)
//
#include <hip/hip_runtime.h>
#include <hip/hip_bf16.h>
#include <math.h>

#define BB 4096
#define LL 16
#define SS 512
#define VV 512
#define II 512
#define HH 512

typedef __attribute__((ext_vector_type(4))) float f32x4;
typedef __attribute__((ext_vector_type(8))) short short8;

#define GLOBAL_AS __attribute__((address_space(1)))
#define LDS_AS __attribute__((address_space(3)))

__device__ __forceinline__ unsigned short f2bf(float f) {
    union { float f; unsigned u; } c; c.f = f;
    unsigned u = c.u + 0x7FFFu + ((c.u >> 16) & 1u);
    return (unsigned short)(u >> 16);
}
__device__ __forceinline__ float bf2f(unsigned short u) {
    union { unsigned u; float f; } c; c.u = ((unsigned)u) << 16;
    return c.f;
}
__device__ __forceinline__ float fast_tanh(float x) {
    return 1.f - 2.f / (__expf(2.f * x) + 1.f);
}

// ---------------------------------------------------------------------------
// MFMA GEMM, m97-style: BM=128, BN=NF*32, BK=64. 256 threads = 4 waves (2x2).
// MODE 0: float out. MODE 1: bf16 out. MODE 2: float out + o_ns row-15 copy.
// ---------------------------------------------------------------------------
template<int MODE, int NF>
__global__ __launch_bounds__(256) void gemm_mfma(
    const ushort* __restrict__ A, const ushort* __restrict__ Bt,
    const float* __restrict__ bias, void* __restrict__ C, float* __restrict__ C2,
    int ldc, int M, int N, int K) {
    constexpr int BN = NF * 32;
    __shared__ ushort Als[128 * 64];
    __shared__ ushort Bls[BN * 64];
    const int tid  = threadIdx.x;
    const int lane = tid & 63;
    const int w    = tid >> 6;
    const int wm   = w >> 1, wn = w & 1;
    const int brow = blockIdx.y * 128;
    const int bcol = blockIdx.x * BN;
    f32x4 acc[4][NF] = {};
    const int nkt = K >> 6;
    for (int kt = 0; kt < nkt; ++kt) {
        __syncthreads();
        #pragma unroll
        for (int i = 0; i < 4; ++i) {
            int c0 = i * 256 + w * 64;
            int c  = c0 + lane;
            int row = c >> 3, sl = c & 7;
            const ushort* gp = A + (size_t)(brow + row) * K + kt * 64 + ((sl ^ (row & 7)) * 8);
            __builtin_amdgcn_global_load_lds((const GLOBAL_AS void*)gp,
                                             (LDS_AS void*)(Als + c0 * 8), 16, 0, 0);
        }
        #pragma unroll
        for (int i = 0; i < NF; ++i) {
            int c0 = i * 256 + w * 64;
            int c  = c0 + lane;
            int row = c >> 3, sl = c & 7;
            const ushort* gp = Bt + (size_t)(bcol + row) * K + kt * 64 + ((sl ^ (row & 7)) * 8);
            __builtin_amdgcn_global_load_lds((const GLOBAL_AS void*)gp,
                                             (LDS_AS void*)(Bls + c0 * 8), 16, 0, 0);
        }
        __syncthreads();
        const char* AlsB = (const char*)Als;
        const char* BlsB = (const char*)Bls;
        #pragma unroll
        for (int kh = 0; kh < 2; ++kh) {
            int ks = kh * 4 + (lane >> 4);
            short8 a[4], b[NF];
            #pragma unroll
            for (int m = 0; m < 4; ++m) {
                int row = wm * 64 + m * 16 + (lane & 15);
                a[m] = *(const short8*)(AlsB + (row * 8 + (ks ^ (row & 7))) * 16);
            }
            #pragma unroll
            for (int n = 0; n < NF; ++n) {
                int row = wn * (NF * 16) + n * 16 + (lane & 15);
                b[n] = *(const short8*)(BlsB + (row * 8 + (ks ^ (row & 7))) * 16);
            }
            #pragma unroll
            for (int m = 0; m < 4; ++m)
                #pragma unroll
                for (int n = 0; n < NF; ++n)
                    acc[m][n] = __builtin_amdgcn_mfma_f32_16x16x32_bf16(a[m], b[n], acc[m][n], 0, 0, 0);
        }
    }
    #pragma unroll
    for (int m = 0; m < 4; ++m)
        #pragma unroll
        for (int n = 0; n < NF; ++n)
            #pragma unroll
            for (int r = 0; r < 4; ++r) {
                int gm = brow + wm * 64 + m * 16 + (lane >> 4) * 4 + r;
                int gc = bcol + wn * (NF * 16) + n * 16 + (lane & 15);
                float v = acc[m][n][r] + bias[gc];
                if (MODE == 1) ((ushort*)C)[(size_t)gm * ldc + gc] = f2bf(v);
                else           ((float*)C)[(size_t)gm * ldc + gc] = v;
                if (MODE == 2) C2[((size_t)gm * 16 + 15) * 512 + gc] = v;
            }
}

// ---------------------------------------------------------------------------
// gemm_x: GEMM1 with A reg-staged directly from fp32 inputs|attns (concat K).
// BM=128, BN=32, BK=64, K=1024 (cols 0..511 inputs, 512..1023 attns).
// bf16 output into A2 (ldc 1024). Kills the A1 buffer + 2 cvt jobs.
// ---------------------------------------------------------------------------
__global__ __launch_bounds__(256) void gemm_x(
    const float* __restrict__ S0, const float* __restrict__ S1,
    const ushort* __restrict__ Bt, const float* __restrict__ bias,
    ushort* __restrict__ C, int ldc) {
    __shared__ ushort Als[128 * 64];
    __shared__ ushort Bls[32 * 64];
    const int tid  = threadIdx.x;
    const int lane = tid & 63;
    const int w    = tid >> 6;
    const int wm   = w >> 1, wn = w & 1;
    const int brow = blockIdx.y * 128;
    const int bcol = blockIdx.x * 32;
    f32x4 acc[4][1] = {};
    for (int kt = 0; kt < 16; ++kt) {
        __syncthreads();
        // A: 1024 chunks, 4/thread, fp32->bf16 cvt, swizzled write (R8 pattern)
        const float* src = (kt < 8) ? S0 : S1;
        const int kbase = (kt & 7) * 64;
        #pragma unroll
        for (int i = 0; i < 4; ++i) {
            int chunk = i * 256 + tid;
            int row = chunk >> 3, slot = chunk & 7;
            int gslot = slot ^ (row & 7);
            const float* gp = src + (size_t)(brow + row) * 512 + kbase + gslot * 8;
            float4 f0 = *(const float4*)gp;
            float4 f1 = *(const float4*)(gp + 4);
            short8 pk;
            pk[0] = (short)f2bf(f0.x); pk[1] = (short)f2bf(f0.y);
            pk[2] = (short)f2bf(f0.z); pk[3] = (short)f2bf(f0.w);
            pk[4] = (short)f2bf(f1.x); pk[5] = (short)f2bf(f1.y);
            pk[6] = (short)f2bf(f1.z); pk[7] = (short)f2bf(f1.w);
            *(short8*)((char*)Als + chunk * 16) = pk;
        }
        // B: 256 chunks via global_load_lds
        {
            int c0 = w * 64;
            int c  = c0 + lane;
            int row = c >> 3, sl = c & 7;
            const ushort* gp = Bt + (size_t)(bcol + row) * 1024 + kt * 64 + ((sl ^ (row & 7)) * 8);
            __builtin_amdgcn_global_load_lds((const GLOBAL_AS void*)gp,
                                             (LDS_AS void*)(Bls + c0 * 8), 16, 0, 0);
        }
        __syncthreads();
        const char* AlsB = (const char*)Als;
        const char* BlsB = (const char*)Bls;
        #pragma unroll
        for (int kh = 0; kh < 2; ++kh) {
            int ks = kh * 4 + (lane >> 4);
            short8 a[4], b;
            #pragma unroll
            for (int m = 0; m < 4; ++m) {
                int row = wm * 64 + m * 16 + (lane & 15);
                a[m] = *(const short8*)(AlsB + (row * 8 + (ks ^ (row & 7))) * 16);
            }
            {
                int row = wn * 16 + (lane & 15);
                b = *(const short8*)(BlsB + (row * 8 + (ks ^ (row & 7))) * 16);
            }
            #pragma unroll
            for (int m = 0; m < 4; ++m)
                acc[m][0] = __builtin_amdgcn_mfma_f32_16x16x32_bf16(a[m], b, acc[m][0], 0, 0, 0);
        }
    }
    #pragma unroll
    for (int m = 0; m < 4; ++m)
        #pragma unroll
        for (int r = 0; r < 4; ++r) {
            int gm = brow + wm * 64 + m * 16 + (lane >> 4) * 4 + r;
            int gc = bcol + wn * 16 + (lane & 15);
            C[(size_t)gm * ldc + gc] = f2bf(acc[m][0][r] + bias[gc]);
        }
}

// ---------------------------------------------------------------------------
// gemm_gates: gates GEMM with FUSED LSTM epilogue (R10-proven).
// ---------------------------------------------------------------------------
__global__ __launch_bounds__(256) void gemm_gates(
    const ushort* __restrict__ A, const ushort* __restrict__ Bt,
    const float* __restrict__ bias, const float* __restrict__ cc,
    float* __restrict__ o_c, float* __restrict__ o_h,
    ushort* __restrict__ A4, ushort* __restrict__ A7) {
    __shared__ ushort Als[128 * 64];
    __shared__ ushort Bls[64 * 64];
    const int tid = threadIdx.x, lane = tid & 63, w = tid >> 6;
    const int l15 = lane & 15, l4 = lane >> 4;
    const int brow = blockIdx.y * 128;
    const int xb = blockIdx.x;
    f32x4 acc[2][4] = {};
    for (int kt = 0; kt < 16; ++kt) {
        __syncthreads();
        #pragma unroll
        for (int i = 0; i < 4; ++i) {
            int c0 = i * 256 + w * 64, c = c0 + lane;
            int row = c >> 3, sl = c & 7;
            const ushort* gp = A + (size_t)(brow + row) * 1024 + kt * 64 + ((sl ^ (row & 7)) * 8);
            __builtin_amdgcn_global_load_lds((const GLOBAL_AS void*)gp,
                                             (LDS_AS void*)(Als + c0 * 8), 16, 0, 0);
        }
        #pragma unroll
        for (int i = 0; i < 2; ++i) {
            int c0 = i * 256 + w * 64, c = c0 + lane;
            int row = c >> 3, sl = c & 7;
            const ushort* gp = Bt + (size_t)(xb * 64 + row) * 1024 + kt * 64 + ((sl ^ (row & 7)) * 8);
            __builtin_amdgcn_global_load_lds((const GLOBAL_AS void*)gp,
                                             (LDS_AS void*)(Bls + c0 * 8), 16, 0, 0);
        }
        __syncthreads();
        const char* AlsB = (const char*)Als;
        const char* BlsB = (const char*)Bls;
        #pragma unroll
        for (int kh = 0; kh < 2; ++kh) {
            int ks = kh * 4 + l4;
            short8 a[2], b[4];
            #pragma unroll
            for (int m = 0; m < 2; ++m) {
                int row = w * 32 + m * 16 + l15;
                a[m] = *(const short8*)(AlsB + (row * 8 + (ks ^ (row & 7))) * 16);
            }
            #pragma unroll
            for (int n = 0; n < 4; ++n) {
                int row = n * 16 + l15;
                b[n] = *(const short8*)(BlsB + (row * 8 + (ks ^ (row & 7))) * 16);
            }
            #pragma unroll
            for (int m = 0; m < 2; ++m)
                #pragma unroll
                for (int n = 0; n < 4; ++n)
                    acc[m][n] = __builtin_amdgcn_mfma_f32_16x16x32_bf16(a[m], b[n], acc[m][n], 0, 0, 0);
        }
    }
    const int h = xb * 16 + l15;
    #pragma unroll
    for (int m = 0; m < 2; ++m)
        #pragma unroll
        for (int r = 0; r < 4; ++r) {
            int gm = brow + w * 32 + m * 16 + l4 * 4 + r;
            float gi = acc[m][0][r] + bias[h];
            float gf = acc[m][1][r] + bias[512 + h];
            float gg = acc[m][2][r] + bias[1024 + h];
            float go = acc[m][3][r] + bias[1536 + h];
            float si = 1.f / (1.f + __expf(-gi));
            float sf = 1.f / (1.f + __expf(-gf));
            float so = 1.f / (1.f + __expf(-go));
            float cv = sf * cc[(size_t)gm * 512 + h] + si * tanhf(gg);
            float hn = so * tanhf(cv);
            o_c[(size_t)gm * 512 + h] = cv;
            o_h[(size_t)gm * 512 + h] = hn;
            A4[(size_t)gm * 1024 + h] = f2bf(cv);
            A4[(size_t)gm * 1024 + 512 + h] = f2bf(hn);
            A7[(size_t)gm * 1024 + h] = f2bf(hn);
        }
}

// ---------------------------------------------------------------------------
// score_all (R9-verified structure + T5 setprio around MFMA cluster):
// BM=64, BN=512, 512 thr = 8 waves, BK=64, global_load_lds B staging,
// reg-staged A cvt, fused softmax + d + o_ns shift.
// ---------------------------------------------------------------------------
__global__ __launch_bounds__(512, 4) void score_all(
    const float* __restrict__ ASf, const ushort* __restrict__ Bt,
    const float* __restrict__ Y, const float* __restrict__ vsum,
    float* __restrict__ o_ns, float* __restrict__ o_d, ushort* __restrict__ A7) {
    __shared__ ushort Als[64 * 64];     // 8 KB
    __shared__ ushort Bls[512 * 64];    // 64 KB
    __shared__ float sred[8][64];
    __shared__ float s_lds[64];
    const int tid  = threadIdx.x;
    const int lane = tid & 63;
    const int w    = tid >> 6;          // 0..7
    const int l15  = lane & 15, l4 = lane >> 4;
    const int brow = blockIdx.x * 64;
    const int bg0  = brow >> 4;         // 4 batches per block
    f32x4 acc[4][4] = {};
    for (int kt = 0; kt < 8; ++kt) {
        __syncthreads();
        // A: 512 16B-chunks, 1/thread, fp32->bf16 cvt, swizzled write
        {
            int chunk = tid;
            int row = chunk >> 3, slot = chunk & 7;
            int gslot = slot ^ (row & 7);
            const float* gp = ASf + (size_t)(brow + row) * 512 + kt * 64 + gslot * 8;
            float4 f0 = *(const float4*)gp;
            float4 f1 = *(const float4*)(gp + 4);
            short8 pk;
            pk[0] = (short)f2bf(f0.x); pk[1] = (short)f2bf(f0.y);
            pk[2] = (short)f2bf(f0.z); pk[3] = (short)f2bf(f0.w);
            pk[4] = (short)f2bf(f1.x); pk[5] = (short)f2bf(f1.y);
            pk[6] = (short)f2bf(f1.z); pk[7] = (short)f2bf(f1.w);
            *(short8*)((char*)Als + chunk * 16) = pk;
        }
        // B: 4096 chunks via global_load_lds (swizzled global source)
        #pragma unroll
        for (int i = 0; i < 8; ++i) {
            int c0 = i * 512 + w * 64;
            int c  = c0 + lane;
            int row = c >> 3, sl = c & 7;
            const ushort* gp = Bt + (size_t)row * 512 + kt * 64 + ((sl ^ (row & 7)) * 8);
            __builtin_amdgcn_global_load_lds((const GLOBAL_AS void*)gp,
                                             (LDS_AS void*)(Bls + c0 * 8), 16, 0, 0);
        }
        __syncthreads();
        const char* AlsB = (const char*)Als;
        const char* BlsB = (const char*)Bls;
        #pragma unroll
        for (int kh = 0; kh < 2; ++kh) {
            int ks = kh * 4 + l4;
            short8 a[4], b[4];
            #pragma unroll
            for (int m = 0; m < 4; ++m) {
                int row = m * 16 + l15;
                a[m] = *(const short8*)(AlsB + (row * 8 + (ks ^ (row & 7))) * 16);
            }
            #pragma unroll
            for (int n = 0; n < 4; ++n) {
                int rowb = w * 64 + n * 16 + l15;
                b[n] = *(const short8*)(BlsB + (rowb * 8 + (ks ^ (rowb & 7))) * 16);
            }
            __builtin_amdgcn_s_setprio(1);
            #pragma unroll
            for (int m = 0; m < 4; ++m)
                #pragma unroll
                for (int n = 0; n < 4; ++n)
                    acc[m][n] = __builtin_amdgcn_mfma_f32_16x16x32_bf16(a[m], b[n], acc[m][n], 0, 0, 0);
            __builtin_amdgcn_s_setprio(0);
        }
    }
    // ---- Phase 2: tanh*vsum epilogue + block-local s reduce ----
    float part[4][4] = {};
    #pragma unroll
    for (int m = 0; m < 4; ++m) {
        int yb = bg0 + m;
        #pragma unroll
        for (int n = 0; n < 4; ++n) {
            int gc = w * 64 + n * 16 + l15;
            float yv = Y[(size_t)yb * 512 + gc];
            float vs = vsum[gc];
            #pragma unroll
            for (int r = 0; r < 4; ++r)
                part[m][r] += fast_tanh(acc[m][n][r] + yv) * vs;
        }
    }
    #pragma unroll
    for (int m = 0; m < 4; ++m)
        #pragma unroll
        for (int r = 0; r < 4; ++r) {
            float v = part[m][r];
            v += __shfl_xor(v, 1); v += __shfl_xor(v, 2);
            v += __shfl_xor(v, 4); v += __shfl_xor(v, 8);
            if (l15 == 0) sred[w][m * 16 + l4 * 4 + r] = v;
        }
    __syncthreads();
    if (tid < 64) {
        float v = 0.f;
        #pragma unroll
        for (int q = 0; q < 8; ++q) v += sred[q][tid];
        s_lds[tid] = v;
    }
    __syncthreads();

    // ---- Phase 3: softmax + d + o_ns shift (re-read own tile, L2/L3-hot) ----
    {
        const int bat = w >> 1;
        const int bg  = bg0 + bat;
        const int c   = (w & 1) * 256 + lane * 4;
        float mx = -1e30f;
        #pragma unroll
        for (int l = 0; l < LL; ++l) mx = fmaxf(mx, s_lds[bat * 16 + l]);
        float wgt[LL]; float sum = 0.f;
        #pragma unroll
        for (int l = 0; l < LL; ++l) { wgt[l] = __expf(s_lds[bat * 16 + l] - mx); sum += wgt[l]; }
        const float inv = 1.f / sum;
        float d0 = 0.f, d1 = 0.f, d2 = 0.f, d3 = 0.f;
        #pragma unroll
        for (int l = 0; l < LL; ++l) {
            float4 v = *(const float4*)(ASf + ((size_t)bg * 16 + l) * 512 + c);
            if (l >= 1)
                *(float4*)(o_ns + ((size_t)bg * 16 + l - 1) * 512 + c) = v;
            d0 += wgt[l] * v.x; d1 += wgt[l] * v.y;
            d2 += wgt[l] * v.z; d3 += wgt[l] * v.w;
        }
        d0 *= inv; d1 *= inv; d2 *= inv; d3 *= inv;
        float4 dv; dv.x = d0; dv.y = d1; dv.z = d2; dv.w = d3;
        *(float4*)(o_d + (size_t)bg * 512 + c) = dv;
        ushort4 uv; uv.x = f2bf(d0); uv.y = f2bf(d1); uv.z = f2bf(d2); uv.w = f2bf(d3);
        *(ushort4*)(A7 + (size_t)bg * 1024 + 512 + c) = uv;
    }
}

// ---------------------------------------------------------------------------
// Merged weight transpose+cvt. perm=1 -> gate-interleaved dst rows.
// ---------------------------------------------------------------------------
struct TrJob { const float* srcA; const float* srcB; int K0; ushort* dst; int N; int K; int perm; };
struct TrJobs { TrJob j[5]; };

__global__ void tr_cvt_all(TrJobs jobs) {
    TrJob jb = jobs.j[blockIdx.z];
    int bn = blockIdx.x, bk = blockIdx.y;
    if (bn * 32 >= jb.N || bk * 32 >= jb.K) return;
    __shared__ float tile[32][33];
    int tx = threadIdx.x, ty = threadIdx.y;
    #pragma unroll
    for (int j = 0; j < 4; ++j) {
        int k = bk * 32 + ty + j * 8;
        const float* s = (k < jb.K0) ? (jb.srcA + (size_t)k * jb.N)
                                     : (jb.srcB + (size_t)(k - jb.K0) * jb.N);
        tile[ty + j * 8][tx] = s[bn * 32 + tx];
    }
    __syncthreads();
    #pragma unroll
    for (int j = 0; j < 4; ++j) {
        int n = bn * 32 + ty + j * 8;
        int nd = n;
        if (jb.perm) {
            int g = n >> 9, u = n & 511;
            nd = (u >> 4) * 64 + g * 16 + (u & 15);
        }
        jb.dst[(size_t)nd * jb.K + bk * 32 + tx] = f2bf(tile[tx][ty + j * 8]);
    }
}

// cell_h fp32 -> bf16 into A2 right half (stride 1024)
__global__ void cvt_ch(const float* __restrict__ src, ushort* __restrict__ dst) {
    int idx = blockIdx.x * 256 + threadIdx.x;
    int i4 = idx & 127, row = idx >> 7;
    float4 v = *(const float4*)(src + (size_t)row * 512 + i4 * 4);
    ushort4 o; o.x = f2bf(v.x); o.y = f2bf(v.y); o.z = f2bf(v.z); o.w = f2bf(v.w);
    *(ushort4*)(dst + (size_t)row * 1024 + i4 * 4) = o;
}

__global__ void vsum_k(const float* __restrict__ Vm, float* __restrict__ out) {
    __shared__ float red[8][32];
    int tc = threadIdx.x & 31, ts = threadIdx.x >> 5;
    int v = blockIdx.x * 32 + tc;
    float acc = 0.f;
    for (int s = ts; s < SS; s += 8) acc += Vm[(size_t)s * VV + v];
    red[ts][tc] = acc;
    __syncthreads();
    if (ts == 0) {
        float t = 0.f;
        #pragma unroll
        for (int j = 0; j < 8; ++j) t += red[j][tc];
        out[v] = t;
    }
}

extern "C" void kernel_launch(void* const* d_in, const int* in_sizes, int n_in,
                              void* d_out, int out_size, void* d_ws, size_t ws_size,
                              hipStream_t stream) {
    const float* inputs      = (const float*)d_in[0];
    const float* cell_c      = (const float*)d_in[1];
    const float* cell_h      = (const float*)d_in[2];
    const float* attns       = (const float*)d_in[3];
    const float* attn_states = (const float*)d_in[4];
    const float* W1          = (const float*)d_in[5];
    const float* b1          = (const float*)d_in[6];
    const float* Wx          = (const float*)d_in[7];
    const float* Wh          = (const float*)d_in[8];
    const float* b_lstm      = (const float*)d_in[9];
    const float* W3          = (const float*)d_in[10];
    const float* b3          = (const float*)d_in[11];
    const float* kmat        = (const float*)d_in[12];
    const float* vmat        = (const float*)d_in[13];
    const float* W2          = (const float*)d_in[14];
    const float* b2          = (const float*)d_in[15];

    float* o_out = (float*)d_out;
    float* o_c   = o_out + (size_t)BB * HH;
    float* o_h   = o_c   + (size_t)BB * HH;
    float* o_d   = o_h   + (size_t)BB * HH;
    float* o_ns  = o_d   + (size_t)BB * SS;

    float* ws_y     = (float*)d_ws;                          // B*V
    float* ws_vsum  = ws_y + (size_t)BB * VV;                // V
    ushort* A2    = (ushort*)(ws_vsum + VV);                 // [B][1024]
    ushort* A4    = A2 + (size_t)BB * 1024;
    ushort* A7    = A4 + (size_t)BB * 1024;
    ushort* W1t   = A7 + (size_t)BB * 1024;                  // [512][1024]
    ushort* WBt   = W1t + (size_t)512 * 1024;                // [2048][1024] gate-interleaved
    ushort* W3t   = WBt + (size_t)2048 * 1024;               // [512][1024]
    ushort* W2t   = W3t + (size_t)512 * 1024;                // [512][1024]
    ushort* kTt   = W2t + (size_t)512 * 1024;                // [512][512]

    TrJobs tj;
    tj.j[0] = {W1, W1, 1024, W1t, 512, 1024, 0};
    tj.j[1] = {Wx, Wh, 512, WBt, 2048, 1024, 1};
    tj.j[2] = {W3, W3, 1024, W3t, 512, 1024, 0};
    tj.j[3] = {W2, W2, 1024, W2t, 512, 1024, 0};
    tj.j[4] = {kmat, kmat, 512, kTt, 512, 512, 0};
    tr_cvt_all<<<dim3(64, 32, 5), dim3(32, 8), 0, stream>>>(tj);
    cvt_ch<<<BB * 128 / 256, 256, 0, stream>>>(cell_h, A2 + 512);
    vsum_k<<<16, 256, 0, stream>>>(vmat, ws_vsum);

    // 1. x = [inputs|attns] @ W1 + b1 -> bf16 into A2 left half (direct fp32 A)
    gemm_x<<<dim3(512 / 32, BB / 128), 256, 0, stream>>>(
        inputs, attns, W1t, b1, A2, 1024);
    // 2+3. gates GEMM with fused LSTM -> o_c, o_h, A4, A7 left half
    gemm_gates<<<dim3(32, BB / 128), 256, 0, stream>>>(
        A2, WBt, b_lstm, cell_c, o_c, o_h, A4, A7);
    // 4. y = [c|h] @ W3 + b3
    gemm_mfma<0, 1><<<dim3(512 / 32, BB / 128), 256, 0, stream>>>(
        A4, W3t, b3, ws_y, nullptr, 512, BB, 512, 1024);
    // 5-6-8a. fused score + softmax + d + o_ns rows 0..14 (R9 structure)
    score_all<<<BB * LL / 64, 512, 0, stream>>>(
        attn_states, kTt, ws_y, ws_vsum, o_ns, o_d, A7);
    // 7+8b. output = [h|d] @ W2 + b2 (also writes o_ns row 15)
    gemm_mfma<2, 1><<<dim3(512 / 32, BB / 128), 256, 0, stream>>>(
        A7, W2t, b2, o_out, o_ns, 512, BB, 512, 1024);
}

// Round 12
// 226.800 us; speedup vs baseline: 1.1304x; 1.1304x over previous
//
#include <hip/hip_runtime.h>
#include <hip/hip_bf16.h>
#include <math.h>

#define BB 4096
#define LL 16
#define SS 512
#define VV 512
#define II 512
#define HH 512

typedef __attribute__((ext_vector_type(4))) float f32x4;
typedef __attribute__((ext_vector_type(8))) short short8;

#define GLOBAL_AS __attribute__((address_space(1)))
#define LDS_AS __attribute__((address_space(3)))

__device__ __forceinline__ unsigned short f2bf(float f) {
    union { float f; unsigned u; } c; c.f = f;
    unsigned u = c.u + 0x7FFFu + ((c.u >> 16) & 1u);
    return (unsigned short)(u >> 16);
}
__device__ __forceinline__ float bf2f(unsigned short u) {
    union { unsigned u; float f; } c; c.u = ((unsigned)u) << 16;
    return c.f;
}
__device__ __forceinline__ float fast_tanh(float x) {
    return 1.f - 2.f / (__expf(2.f * x) + 1.f);
}

// ---------------------------------------------------------------------------
// MFMA GEMM, m97-style: BM=128, BN=NF*32, BK=64. 256 threads = 4 waves (2x2).
// MODE 0: float out. MODE 1: bf16 out. MODE 2: float out + o_ns row-15 copy.
// ---------------------------------------------------------------------------
template<int MODE, int NF>
__global__ __launch_bounds__(256) void gemm_mfma(
    const ushort* __restrict__ A, const ushort* __restrict__ Bt,
    const float* __restrict__ bias, void* __restrict__ C, float* __restrict__ C2,
    int ldc, int M, int N, int K) {
    constexpr int BN = NF * 32;
    __shared__ ushort Als[128 * 64];
    __shared__ ushort Bls[BN * 64];
    const int tid  = threadIdx.x;
    const int lane = tid & 63;
    const int w    = tid >> 6;
    const int wm   = w >> 1, wn = w & 1;
    const int brow = blockIdx.y * 128;
    const int bcol = blockIdx.x * BN;
    f32x4 acc[4][NF] = {};
    const int nkt = K >> 6;
    for (int kt = 0; kt < nkt; ++kt) {
        __syncthreads();
        #pragma unroll
        for (int i = 0; i < 4; ++i) {
            int c0 = i * 256 + w * 64;
            int c  = c0 + lane;
            int row = c >> 3, sl = c & 7;
            const ushort* gp = A + (size_t)(brow + row) * K + kt * 64 + ((sl ^ (row & 7)) * 8);
            __builtin_amdgcn_global_load_lds((const GLOBAL_AS void*)gp,
                                             (LDS_AS void*)(Als + c0 * 8), 16, 0, 0);
        }
        #pragma unroll
        for (int i = 0; i < NF; ++i) {
            int c0 = i * 256 + w * 64;
            int c  = c0 + lane;
            int row = c >> 3, sl = c & 7;
            const ushort* gp = Bt + (size_t)(bcol + row) * K + kt * 64 + ((sl ^ (row & 7)) * 8);
            __builtin_amdgcn_global_load_lds((const GLOBAL_AS void*)gp,
                                             (LDS_AS void*)(Bls + c0 * 8), 16, 0, 0);
        }
        __syncthreads();
        const char* AlsB = (const char*)Als;
        const char* BlsB = (const char*)Bls;
        #pragma unroll
        for (int kh = 0; kh < 2; ++kh) {
            int ks = kh * 4 + (lane >> 4);
            short8 a[4], b[NF];
            #pragma unroll
            for (int m = 0; m < 4; ++m) {
                int row = wm * 64 + m * 16 + (lane & 15);
                a[m] = *(const short8*)(AlsB + (row * 8 + (ks ^ (row & 7))) * 16);
            }
            #pragma unroll
            for (int n = 0; n < NF; ++n) {
                int row = wn * (NF * 16) + n * 16 + (lane & 15);
                b[n] = *(const short8*)(BlsB + (row * 8 + (ks ^ (row & 7))) * 16);
            }
            #pragma unroll
            for (int m = 0; m < 4; ++m)
                #pragma unroll
                for (int n = 0; n < NF; ++n)
                    acc[m][n] = __builtin_amdgcn_mfma_f32_16x16x32_bf16(a[m], b[n], acc[m][n], 0, 0, 0);
        }
    }
    #pragma unroll
    for (int m = 0; m < 4; ++m)
        #pragma unroll
        for (int n = 0; n < NF; ++n)
            #pragma unroll
            for (int r = 0; r < 4; ++r) {
                int gm = brow + wm * 64 + m * 16 + (lane >> 4) * 4 + r;
                int gc = bcol + wn * (NF * 16) + n * 16 + (lane & 15);
                float v = acc[m][n][r] + bias[gc];
                if (MODE == 1) ((ushort*)C)[(size_t)gm * ldc + gc] = f2bf(v);
                else           ((float*)C)[(size_t)gm * ldc + gc] = v;
                if (MODE == 2) C2[((size_t)gm * 16 + 15) * 512 + gc] = v;
            }
}

// ---------------------------------------------------------------------------
// gemm_gates: gates GEMM with FUSED LSTM epilogue (R10-proven).
// ---------------------------------------------------------------------------
__global__ __launch_bounds__(256) void gemm_gates(
    const ushort* __restrict__ A, const ushort* __restrict__ Bt,
    const float* __restrict__ bias, const float* __restrict__ cc,
    float* __restrict__ o_c, float* __restrict__ o_h,
    ushort* __restrict__ A4, ushort* __restrict__ A7) {
    __shared__ ushort Als[128 * 64];
    __shared__ ushort Bls[64 * 64];
    const int tid = threadIdx.x, lane = tid & 63, w = tid >> 6;
    const int l15 = lane & 15, l4 = lane >> 4;
    const int brow = blockIdx.y * 128;
    const int xb = blockIdx.x;
    f32x4 acc[2][4] = {};
    for (int kt = 0; kt < 16; ++kt) {
        __syncthreads();
        #pragma unroll
        for (int i = 0; i < 4; ++i) {
            int c0 = i * 256 + w * 64, c = c0 + lane;
            int row = c >> 3, sl = c & 7;
            const ushort* gp = A + (size_t)(brow + row) * 1024 + kt * 64 + ((sl ^ (row & 7)) * 8);
            __builtin_amdgcn_global_load_lds((const GLOBAL_AS void*)gp,
                                             (LDS_AS void*)(Als + c0 * 8), 16, 0, 0);
        }
        #pragma unroll
        for (int i = 0; i < 2; ++i) {
            int c0 = i * 256 + w * 64, c = c0 + lane;
            int row = c >> 3, sl = c & 7;
            const ushort* gp = Bt + (size_t)(xb * 64 + row) * 1024 + kt * 64 + ((sl ^ (row & 7)) * 8);
            __builtin_amdgcn_global_load_lds((const GLOBAL_AS void*)gp,
                                             (LDS_AS void*)(Bls + c0 * 8), 16, 0, 0);
        }
        __syncthreads();
        const char* AlsB = (const char*)Als;
        const char* BlsB = (const char*)Bls;
        #pragma unroll
        for (int kh = 0; kh < 2; ++kh) {
            int ks = kh * 4 + l4;
            short8 a[2], b[4];
            #pragma unroll
            for (int m = 0; m < 2; ++m) {
                int row = w * 32 + m * 16 + l15;
                a[m] = *(const short8*)(AlsB + (row * 8 + (ks ^ (row & 7))) * 16);
            }
            #pragma unroll
            for (int n = 0; n < 4; ++n) {
                int row = n * 16 + l15;
                b[n] = *(const short8*)(BlsB + (row * 8 + (ks ^ (row & 7))) * 16);
            }
            #pragma unroll
            for (int m = 0; m < 2; ++m)
                #pragma unroll
                for (int n = 0; n < 4; ++n)
                    acc[m][n] = __builtin_amdgcn_mfma_f32_16x16x32_bf16(a[m], b[n], acc[m][n], 0, 0, 0);
        }
    }
    const int h = xb * 16 + l15;
    #pragma unroll
    for (int m = 0; m < 2; ++m)
        #pragma unroll
        for (int r = 0; r < 4; ++r) {
            int gm = brow + w * 32 + m * 16 + l4 * 4 + r;
            float gi = acc[m][0][r] + bias[h];
            float gf = acc[m][1][r] + bias[512 + h];
            float gg = acc[m][2][r] + bias[1024 + h];
            float go = acc[m][3][r] + bias[1536 + h];
            float si = 1.f / (1.f + __expf(-gi));
            float sf = 1.f / (1.f + __expf(-gf));
            float so = 1.f / (1.f + __expf(-go));
            float cv = sf * cc[(size_t)gm * 512 + h] + si * tanhf(gg);
            float hn = so * tanhf(cv);
            o_c[(size_t)gm * 512 + h] = cv;
            o_h[(size_t)gm * 512 + h] = hn;
            A4[(size_t)gm * 1024 + h] = f2bf(cv);
            A4[(size_t)gm * 1024 + 512 + h] = f2bf(hn);
            A7[(size_t)gm * 1024 + h] = f2bf(hn);
        }
}

// ---------------------------------------------------------------------------
// score_all (R9-verified; B global_load_lds issued BEFORE A reg-stage so the
// B flight hides under the A cvt work): BM=64, BN=512, 8 waves, BK=64.
// ---------------------------------------------------------------------------
__global__ __launch_bounds__(512, 4) void score_all(
    const float* __restrict__ ASf, const ushort* __restrict__ Bt,
    const float* __restrict__ Y, const float* __restrict__ vsum,
    float* __restrict__ o_ns, float* __restrict__ o_d, ushort* __restrict__ A7) {
    __shared__ ushort Als[64 * 64];     // 8 KB
    __shared__ ushort Bls[512 * 64];    // 64 KB
    __shared__ float sred[8][64];
    __shared__ float s_lds[64];
    const int tid  = threadIdx.x;
    const int lane = tid & 63;
    const int w    = tid >> 6;          // 0..7
    const int l15  = lane & 15, l4 = lane >> 4;
    const int brow = blockIdx.x * 64;
    const int bg0  = brow >> 4;         // 4 batches per block
    f32x4 acc[4][4] = {};
    for (int kt = 0; kt < 8; ++kt) {
        __syncthreads();
        // B first: 4096 chunks via global_load_lds (latency hides under A cvt)
        #pragma unroll
        for (int i = 0; i < 8; ++i) {
            int c0 = i * 512 + w * 64;
            int c  = c0 + lane;
            int row = c >> 3, sl = c & 7;
            const ushort* gp = Bt + (size_t)row * 512 + kt * 64 + ((sl ^ (row & 7)) * 8);
            __builtin_amdgcn_global_load_lds((const GLOBAL_AS void*)gp,
                                             (LDS_AS void*)(Bls + c0 * 8), 16, 0, 0);
        }
        // A: 512 16B-chunks, 1/thread, fp32->bf16 cvt, swizzled write
        {
            int chunk = tid;
            int row = chunk >> 3, slot = chunk & 7;
            int gslot = slot ^ (row & 7);
            const float* gp = ASf + (size_t)(brow + row) * 512 + kt * 64 + gslot * 8;
            float4 f0 = *(const float4*)gp;
            float4 f1 = *(const float4*)(gp + 4);
            short8 pk;
            pk[0] = (short)f2bf(f0.x); pk[1] = (short)f2bf(f0.y);
            pk[2] = (short)f2bf(f0.z); pk[3] = (short)f2bf(f0.w);
            pk[4] = (short)f2bf(f1.x); pk[5] = (short)f2bf(f1.y);
            pk[6] = (short)f2bf(f1.z); pk[7] = (short)f2bf(f1.w);
            *(short8*)((char*)Als + chunk * 16) = pk;
        }
        __syncthreads();
        const char* AlsB = (const char*)Als;
        const char* BlsB = (const char*)Bls;
        #pragma unroll
        for (int kh = 0; kh < 2; ++kh) {
            int ks = kh * 4 + l4;
            short8 a[4], b[4];
            #pragma unroll
            for (int m = 0; m < 4; ++m) {
                int row = m * 16 + l15;
                a[m] = *(const short8*)(AlsB + (row * 8 + (ks ^ (row & 7))) * 16);
            }
            #pragma unroll
            for (int n = 0; n < 4; ++n) {
                int rowb = w * 64 + n * 16 + l15;
                b[n] = *(const short8*)(BlsB + (rowb * 8 + (ks ^ (rowb & 7))) * 16);
            }
            #pragma unroll
            for (int m = 0; m < 4; ++m)
                #pragma unroll
                for (int n = 0; n < 4; ++n)
                    acc[m][n] = __builtin_amdgcn_mfma_f32_16x16x32_bf16(a[m], b[n], acc[m][n], 0, 0, 0);
        }
    }
    // ---- Phase 2: tanh*vsum epilogue + block-local s reduce ----
    float part[4][4] = {};
    #pragma unroll
    for (int m = 0; m < 4; ++m) {
        int yb = bg0 + m;
        #pragma unroll
        for (int n = 0; n < 4; ++n) {
            int gc = w * 64 + n * 16 + l15;
            float yv = Y[(size_t)yb * 512 + gc];
            float vs = vsum[gc];
            #pragma unroll
            for (int r = 0; r < 4; ++r)
                part[m][r] += fast_tanh(acc[m][n][r] + yv) * vs;
        }
    }
    #pragma unroll
    for (int m = 0; m < 4; ++m)
        #pragma unroll
        for (int r = 0; r < 4; ++r) {
            float v = part[m][r];
            v += __shfl_xor(v, 1); v += __shfl_xor(v, 2);
            v += __shfl_xor(v, 4); v += __shfl_xor(v, 8);
            if (l15 == 0) sred[w][m * 16 + l4 * 4 + r] = v;
        }
    __syncthreads();
    if (tid < 64) {
        float v = 0.f;
        #pragma unroll
        for (int q = 0; q < 8; ++q) v += sred[q][tid];
        s_lds[tid] = v;
    }
    __syncthreads();

    // ---- Phase 3: softmax + d + o_ns shift (re-read own tile, L2/L3-hot) ----
    {
        const int bat = w >> 1;
        const int bg  = bg0 + bat;
        const int c   = (w & 1) * 256 + lane * 4;
        float mx = -1e30f;
        #pragma unroll
        for (int l = 0; l < LL; ++l) mx = fmaxf(mx, s_lds[bat * 16 + l]);
        float wgt[LL]; float sum = 0.f;
        #pragma unroll
        for (int l = 0; l < LL; ++l) { wgt[l] = __expf(s_lds[bat * 16 + l] - mx); sum += wgt[l]; }
        const float inv = 1.f / sum;
        float d0 = 0.f, d1 = 0.f, d2 = 0.f, d3 = 0.f;
        #pragma unroll
        for (int l = 0; l < LL; ++l) {
            float4 v = *(const float4*)(ASf + ((size_t)bg * 16 + l) * 512 + c);
            if (l >= 1)
                *(float4*)(o_ns + ((size_t)bg * 16 + l - 1) * 512 + c) = v;
            d0 += wgt[l] * v.x; d1 += wgt[l] * v.y;
            d2 += wgt[l] * v.z; d3 += wgt[l] * v.w;
        }
        d0 *= inv; d1 *= inv; d2 *= inv; d3 *= inv;
        float4 dv; dv.x = d0; dv.y = d1; dv.z = d2; dv.w = d3;
        *(float4*)(o_d + (size_t)bg * 512 + c) = dv;
        ushort4 uv; uv.x = f2bf(d0); uv.y = f2bf(d1); uv.z = f2bf(d2); uv.w = f2bf(d3);
        *(ushort4*)(A7 + (size_t)bg * 1024 + 512 + c) = uv;
    }
}

// ---------------------------------------------------------------------------
// Merged weight transpose+cvt. perm=1 -> gate-interleaved dst rows.
// ---------------------------------------------------------------------------
struct TrJob { const float* srcA; const float* srcB; int K0; ushort* dst; int N; int K; int perm; };
struct TrJobs { TrJob j[5]; };

__global__ void tr_cvt_all(TrJobs jobs) {
    TrJob jb = jobs.j[blockIdx.z];
    int bn = blockIdx.x, bk = blockIdx.y;
    if (bn * 32 >= jb.N || bk * 32 >= jb.K) return;
    __shared__ float tile[32][33];
    int tx = threadIdx.x, ty = threadIdx.y;
    #pragma unroll
    for (int j = 0; j < 4; ++j) {
        int k = bk * 32 + ty + j * 8;
        const float* s = (k < jb.K0) ? (jb.srcA + (size_t)k * jb.N)
                                     : (jb.srcB + (size_t)(k - jb.K0) * jb.N);
        tile[ty + j * 8][tx] = s[bn * 32 + tx];
    }
    __syncthreads();
    #pragma unroll
    for (int j = 0; j < 4; ++j) {
        int n = bn * 32 + ty + j * 8;
        int nd = n;
        if (jb.perm) {
            int g = n >> 9, u = n & 511;
            nd = (u >> 4) * 64 + g * 16 + (u & 15);
        }
        jb.dst[(size_t)nd * jb.K + bk * 32 + tx] = f2bf(tile[tx][ty + j * 8]);
    }
}

// Merged activation cvt (inputs/attns/cell_h -> bf16 halves of A1/A2)
struct CvJobs { const float* src[3]; ushort* dst[3]; };
__global__ void cvt_all(CvJobs jobs) {
    const float* src = jobs.src[blockIdx.y];
    ushort* dst = jobs.dst[blockIdx.y];
    int idx = blockIdx.x * 256 + threadIdx.x;
    int i4 = idx & 127, row = idx >> 7;
    float4 v = *(const float4*)(src + (size_t)row * 512 + i4 * 4);
    ushort4 o; o.x = f2bf(v.x); o.y = f2bf(v.y); o.z = f2bf(v.z); o.w = f2bf(v.w);
    *(ushort4*)(dst + (size_t)row * 1024 + i4 * 4) = o;
}

__global__ void vsum_k(const float* __restrict__ Vm, float* __restrict__ out) {
    __shared__ float red[8][32];
    int tc = threadIdx.x & 31, ts = threadIdx.x >> 5;
    int v = blockIdx.x * 32 + tc;
    float acc = 0.f;
    for (int s = ts; s < SS; s += 8) acc += Vm[(size_t)s * VV + v];
    red[ts][tc] = acc;
    __syncthreads();
    if (ts == 0) {
        float t = 0.f;
        #pragma unroll
        for (int j = 0; j < 8; ++j) t += red[j][tc];
        out[v] = t;
    }
}

extern "C" void kernel_launch(void* const* d_in, const int* in_sizes, int n_in,
                              void* d_out, int out_size, void* d_ws, size_t ws_size,
                              hipStream_t stream) {
    const float* inputs      = (const float*)d_in[0];
    const float* cell_c      = (const float*)d_in[1];
    const float* cell_h      = (const float*)d_in[2];
    const float* attns       = (const float*)d_in[3];
    const float* attn_states = (const float*)d_in[4];
    const float* W1          = (const float*)d_in[5];
    const float* b1          = (const float*)d_in[6];
    const float* Wx          = (const float*)d_in[7];
    const float* Wh          = (const float*)d_in[8];
    const float* b_lstm      = (const float*)d_in[9];
    const float* W3          = (const float*)d_in[10];
    const float* b3          = (const float*)d_in[11];
    const float* kmat        = (const float*)d_in[12];
    const float* vmat        = (const float*)d_in[13];
    const float* W2          = (const float*)d_in[14];
    const float* b2          = (const float*)d_in[15];

    float* o_out = (float*)d_out;
    float* o_c   = o_out + (size_t)BB * HH;
    float* o_h   = o_c   + (size_t)BB * HH;
    float* o_d   = o_h   + (size_t)BB * HH;
    float* o_ns  = o_d   + (size_t)BB * SS;

    float* ws_y     = (float*)d_ws;                          // B*V
    float* ws_vsum  = ws_y + (size_t)BB * VV;                // V
    ushort* A1    = (ushort*)(ws_vsum + VV);                 // [B][1024]
    ushort* A2    = A1 + (size_t)BB * 1024;
    ushort* A4    = A2 + (size_t)BB * 1024;
    ushort* A7    = A4 + (size_t)BB * 1024;
    ushort* W1t   = A7 + (size_t)BB * 1024;                  // [512][1024]
    ushort* WBt   = W1t + (size_t)512 * 1024;                // [2048][1024] gate-interleaved
    ushort* W3t   = WBt + (size_t)2048 * 1024;               // [512][1024]
    ushort* W2t   = W3t + (size_t)512 * 1024;                // [512][1024]
    ushort* kTt   = W2t + (size_t)512 * 1024;                // [512][512]

    TrJobs tj;
    tj.j[0] = {W1, W1, 1024, W1t, 512, 1024, 0};
    tj.j[1] = {Wx, Wh, 512, WBt, 2048, 1024, 1};
    tj.j[2] = {W3, W3, 1024, W3t, 512, 1024, 0};
    tj.j[3] = {W2, W2, 1024, W2t, 512, 1024, 0};
    tj.j[4] = {kmat, kmat, 512, kTt, 512, 512, 0};
    tr_cvt_all<<<dim3(64, 32, 5), dim3(32, 8), 0, stream>>>(tj);
    CvJobs cj;
    cj.src[0] = inputs; cj.dst[0] = A1;
    cj.src[1] = attns;  cj.dst[1] = A1 + 512;
    cj.src[2] = cell_h; cj.dst[2] = A2 + 512;
    cvt_all<<<dim3(BB * 128 / 256, 3), 256, 0, stream>>>(cj);
    vsum_k<<<16, 256, 0, stream>>>(vmat, ws_vsum);

    // 1. x = [inputs|attns] @ W1 + b1 -> bf16 into A2 left half
    gemm_mfma<1, 1><<<dim3(512 / 32, BB / 128), 256, 0, stream>>>(
        A1, W1t, b1, A2, nullptr, 1024, BB, 512, 1024);
    // 2+3. gates GEMM with fused LSTM -> o_c, o_h, A4, A7 left half
    gemm_gates<<<dim3(32, BB / 128), 256, 0, stream>>>(
        A2, WBt, b_lstm, cell_c, o_c, o_h, A4, A7);
    // 4. y = [c|h] @ W3 + b3
    gemm_mfma<0, 1><<<dim3(512 / 32, BB / 128), 256, 0, stream>>>(
        A4, W3t, b3, ws_y, nullptr, 512, BB, 512, 1024);
    // 5-6-8a. fused score + softmax + d + o_ns rows 0..14 (R9 structure, B-first)
    score_all<<<BB * LL / 64, 512, 0, stream>>>(
        attn_states, kTt, ws_y, ws_vsum, o_ns, o_d, A7);
    // 7+8b. output = [h|d] @ W2 + b2 (also writes o_ns row 15)
    gemm_mfma<2, 1><<<dim3(512 / 32, BB / 128), 256, 0, stream>>>(
        A7, W2t, b2, o_out, o_ns, 512, BB, 512, 1024);
}